// Round 16
// baseline (2196.962 us; speedup 1.0000x reference)
//
#include <hip/hip_runtime.h>
#include <hip/hip_bf16.h>
#include <math.h>

#define L_ 12
#define C_ 768
#define H_ 12
#define FF_ 3072
#define V_ 50257
#define VP2_ 50432   // V padded to multiple of 256
#define T_ 512
#define B_ 4
#define D_ 64
#define M_ (B_*T_)   // 2048 rows
#define BH_ (B_*H_)  // 48
#define NPAN_LM 197  // VP2_/256

typedef __attribute__((ext_vector_type(8))) short short8;
typedef __attribute__((ext_vector_type(4))) float f32x4;
typedef __attribute__((ext_vector_type(8))) unsigned short us8;
typedef __attribute__((ext_vector_type(4))) unsigned short us4;

__device__ __forceinline__ float bf2f(unsigned short u) {
    return __uint_as_float(((unsigned)u) << 16);
}
__device__ __forceinline__ unsigned short f2bf(float f) {
    unsigned u = __float_as_uint(f);
    unsigned r = u + 0x7fff + ((u >> 16) & 1);   // RNE
    return (unsigned short)(r >> 16);
}

// ---------------- fused weight convert+transpose (all 5 weight groups, 1 dispatch) ---------
__device__ __forceinline__ void transpose_tile(
    const float* __restrict__ W, __hip_bfloat16* __restrict__ WT,
    int K, int N, int Npad, int bx, int by, int bz)
{
    __shared__ float tile[64][65];
    const float* Wl = W + (size_t)bz * K * N;
    __hip_bfloat16* WTl = WT + (size_t)bz * Npad * K;
    int k0 = by * 64, n0 = bx * 64;
    int tid = threadIdx.x;
    int tn = tid & 63, tk4 = tid >> 6;
#pragma unroll 4
    for (int i = 0; i < 16; ++i) {
        int k = tk4 * 16 + i;
        int n = n0 + tn;
        tile[k][tn] = (n < N) ? Wl[(size_t)(k0 + k) * N + n] : 0.f;
    }
    __syncthreads();
#pragma unroll
    for (int i = 0; i < 2; ++i) {
        int p = tid + i * 256;
        int n = p >> 3;
        int k8 = (p & 7) * 8;
        us8 v;
#pragma unroll
        for (int e = 0; e < 8; ++e) v[e] = f2bf(tile[k8 + e][n]);
        *(us8*)((unsigned short*)WTl + (size_t)(n0 + n) * K + k0 + k8) = v;
    }
}

__global__ __launch_bounds__(256) void transpose_all_kernel(
    const float* W0, __hip_bfloat16* T0,
    const float* W1, __hip_bfloat16* T1,
    const float* W2, __hip_bfloat16* T2,
    const float* W3, __hip_bfloat16* T3,
    const float* W4, __hip_bfloat16* T4)
{
    int bid = blockIdx.x;
    if (bid < 5184) {
        int bx = bid % 36, r = bid / 36;
        transpose_tile(W0, T0, C_, 3 * C_, 3 * C_, bx, r % 12, r / 12);
    } else if (bid < 6912) {
        int lb = bid - 5184;
        int bx = lb % 12, r = lb / 12;
        transpose_tile(W1, T1, C_, C_, C_, bx, r % 12, r / 12);
    } else if (bid < 13824) {
        int lb = bid - 6912;
        int bx = lb % 48, r = lb / 48;
        transpose_tile(W2, T2, C_, FF_, FF_, bx, r % 12, r / 12);
    } else if (bid < 20736) {
        int lb = bid - 13824;
        int bx = lb % 12, r = lb / 12;
        transpose_tile(W3, T3, FF_, C_, C_, bx, r % 48, r / 48);
    } else {
        int lb = bid - 20736;
        int bx = lb % 788, by = lb / 788;
        transpose_tile(W4, T4, C_, V_, VP2_, bx, by, 0);
    }
}

// ---------------- embedding (fp32 residual stream), vectorized f32x4 ----------------
__global__ __launch_bounds__(256) void embed_kernel(
    const int* __restrict__ idx, const float* __restrict__ wte,
    const float* __restrict__ wpe, float* __restrict__ x, int total4)
{
    int i = blockIdx.x * blockDim.x + threadIdx.x;
    if (i >= total4) return;
    const int CQ = C_ / 4;
    int c4 = (i % CQ) * 4;
    int row = i / CQ;
    int t = row % T_;
    f32x4 a = *(const f32x4*)(wte + (size_t)idx[row] * C_ + c4);
    f32x4 b = *(const f32x4*)(wpe + (size_t)t * C_ + c4);
    *(f32x4*)(x + (size_t)row * C_ + c4) = a + b;
}

// ---------------- layernorm: wave-per-row, zero barriers ----------------
__global__ __launch_bounds__(256) void layernorm_kernel(
    const float* __restrict__ x, const float* __restrict__ w, const float* __restrict__ b,
    __hip_bfloat16* __restrict__ out)
{
    int wv = threadIdx.x >> 6, lane = threadIdx.x & 63;
    int row = blockIdx.x * 4 + wv;
    const float* xr = x + (size_t)row * C_;
    f32x4 v[3];
    float s = 0.f;
#pragma unroll
    for (int j = 0; j < 3; ++j) {
        v[j] = *(const f32x4*)(xr + j * 256 + lane * 4);
        s += v[j][0] + v[j][1] + v[j][2] + v[j][3];
    }
#pragma unroll
    for (int off = 32; off; off >>= 1) s += __shfl_xor(s, off, 64);
    float mean = s * (1.f / (float)C_);
    float var = 0.f;
#pragma unroll
    for (int j = 0; j < 3; ++j)
#pragma unroll
        for (int e = 0; e < 4; ++e) { float d = v[j][e] - mean; var += d * d; }
#pragma unroll
    for (int off = 32; off; off >>= 1) var += __shfl_xor(var, off, 64);
    float rstd = rsqrtf(var * (1.f / (float)C_) + 1e-5f);
    unsigned short* o = (unsigned short*)out + (size_t)row * C_;
#pragma unroll
    for (int j = 0; j < 3; ++j) {
        int c0 = j * 256 + lane * 4;
        f32x4 wv4 = *(const f32x4*)(w + c0);
        f32x4 bv4 = *(const f32x4*)(b + c0);
        us4 u;
#pragma unroll
        for (int e = 0; e < 4; ++e)
            u[e] = f2bf((v[j][e] - mean) * rstd * wv4[e] + bv4[e]);
        *(us4*)(o + c0) = u;
    }
}

// ---------------- bf16 MFMA GEMM, pipelined + LDS-swizzled ----------------
// MT x NT tile, WM x WN waves, BK=32, BUFS-buffer LDS, depth-(BUFS-1) prefetch,
// tail-aware counted vmcnt, bijective XCD swizzle (m204). SPLITK chunks the K range;
// ATOMIC epilogue accumulates fp32 partials into Cout (in-place residual), bias on chunk 0.
// BUFS=2: stage(t+1) issued before do_tile(t), drained at next iter's vmcnt(0) — one full
// K-step of in-flight time (not the m97 stage->drain->compute antipattern).
template<int MT, int NT, int WM, int WN, int BUFS, int SPLITK,
         int OUTBF, int GELU, int RESID, int LOSSP, int QKVPACK, int ATOMIC>
__global__ __launch_bounds__(64 * WM * WN) void mfma_gemm(
    const __hip_bfloat16* __restrict__ A,
    const __hip_bfloat16* __restrict__ Bt,
    const float* __restrict__ bias,
    const float* __restrict__ resid,
    void* __restrict__ Cout,
    int M, int N, int K, int NB,
    float* __restrict__ lpart, int NPAN,
    unsigned short* __restrict__ Qp, unsigned short* __restrict__ Kp,
    unsigned short* __restrict__ Vt)
{
    constexpr int NTHREADS = 64 * WM * WN;
    constexpr int MPAN = M_ / MT;
    constexpr int MFR = MT / (16 * WM);      // per-wave m-fragments
    constexpr int AL = (MT * 4) / NTHREADS;
    constexpr int BL = (NT * 4) / NTHREADS;
    constexpr int LOADS = AL + BL;

    int nwg = NB * MPAN * SPLITK;
    int orig = blockIdx.x;
    int xcd = orig & 7;
    int q = nwg >> 3, rr_ = nwg & 7;
    int wgid = (xcd < rr_ ? xcd * (q + 1) : rr_ * (q + 1) + (xcd - rr_) * q) + (orig >> 3);
    int chunk = wgid / (NB * MPAN);
    int rem = wgid % (NB * MPAN);
    int npan = rem / MPAN, mpan = rem % MPAN;
    int m0 = mpan * MT, n0 = npan * NT;
    int KC = K / SPLITK;
    int kbase = chunk * KC;

    __shared__ __hip_bfloat16 As[BUFS][MT * 32];
    __shared__ __hip_bfloat16 Bs[BUFS][NT * 32];
    __shared__ float Lsum[WN][LOSSP ? MT : 1];
    int tid = threadIdx.x;
    int lane = tid & 63, w = tid >> 6;
    int wn = w % WN, wm = w / WN;
    int lrow = lane & 15, g = lane >> 4;
    f32x4 acc[MFR][4] = {};

    const __hip_bfloat16* Ab = A + (size_t)m0 * K + kbase;
    const __hip_bfloat16* Bb = Bt + (size_t)n0 * K + kbase;

    auto stage = [&](int buf, int k0) {
#pragma unroll
        for (int i = 0; i < AL; ++i) {
            int c = tid + i * NTHREADS;
            int row = c >> 2, s = c & 3;
            int l = (s - (row >> 1)) & 3;            // inverse-swizzled source slot
            __builtin_amdgcn_global_load_lds(
                (const __attribute__((address_space(1))) void*)(Ab + (size_t)row * K + k0 + l * 8),
                (__attribute__((address_space(3))) void*)(&As[buf][c * 8]), 16, 0, 0);
        }
#pragma unroll
        for (int i = 0; i < BL; ++i) {
            int c = tid + i * NTHREADS;
            int row = c >> 2, s = c & 3;
            int l = (s - (row >> 1)) & 3;
            __builtin_amdgcn_global_load_lds(
                (const __attribute__((address_space(1))) void*)(Bb + (size_t)row * K + k0 + l * 8),
                (__attribute__((address_space(3))) void*)(&Bs[buf][c * 8]), 16, 0, 0);
        }
    };
    auto do_tile = [&](int buf) {
        short8 a[MFR], b[4];
#pragma unroll
        for (int i = 0; i < MFR; ++i) {
            int row = wm * (MT / WM) + i * 16 + lrow;
            int s = (g + (row >> 1)) & 3;            // swizzled read slot
            a[i] = *(const short8*)&As[buf][row * 32 + s * 8];
        }
#pragma unroll
        for (int j = 0; j < 4; ++j) {
            int row = wn * 64 + j * 16 + lrow;
            int s = (g + (row >> 1)) & 3;
            b[j] = *(const short8*)&Bs[buf][row * 32 + s * 8];
        }
        asm volatile("s_waitcnt lgkmcnt(0)" ::: "memory");
        __builtin_amdgcn_sched_barrier(0);
        __builtin_amdgcn_s_setprio(1);
#pragma unroll
        for (int i = 0; i < MFR; ++i)
#pragma unroll
            for (int j = 0; j < 4; ++j)
                acc[i][j] = __builtin_amdgcn_mfma_f32_16x16x32_bf16(a[i], b[j], acc[i][j], 0, 0, 0);
        __builtin_amdgcn_s_setprio(0);
    };

    int nk = KC >> 5;
#pragma unroll
    for (int i = 0; i < BUFS - 1; ++i) stage(i, i << 5);
    for (int t = 0; t < nk; ++t) {
        int ahead = nk - 1 - t;
        if (ahead > BUFS - 2) ahead = BUFS - 2;
        if (ahead == 1) {
            if constexpr (LOADS == 3) asm volatile("s_waitcnt vmcnt(3)" ::: "memory");
            else                      asm volatile("s_waitcnt vmcnt(4)" ::: "memory");
        } else if (ahead >= 2) {
            if constexpr (LOADS == 3) asm volatile("s_waitcnt vmcnt(6)" ::: "memory");
            else                      asm volatile("s_waitcnt vmcnt(8)" ::: "memory");
        } else {
            asm volatile("s_waitcnt vmcnt(0)" ::: "memory");
        }
        __builtin_amdgcn_s_barrier();
        if (t + BUFS - 1 < nk) stage((t + BUFS - 1) % BUFS, (t + BUFS - 1) << 5);
        do_tile(t % BUFS);
    }

    int r0 = g * 4;
    if (QKVPACK) {
        // which (q/k/v section) is block-uniform: n0 is 128-aligned, sections 768-aligned
        int which = n0 / 768;
#pragma unroll
        for (int i = 0; i < MFR; ++i) {
#pragma unroll
            for (int j = 0; j < 4; ++j) {
                int col = n0 + wn * 64 + j * 16 + lrow;
                float bv = bias ? bias[col] : 0.f;
                int cc = col - which * 768;
                int hh = cc >> 6, d = cc & 63;
                int row0 = m0 + wm * (MT / WM) + i * 16 + r0;
                int bb = row0 >> 9, tt0 = row0 & (T_ - 1);
                size_t bh = (size_t)bb * H_ + hh;
                if (which == 2) {
                    // V transposed: r=0..3 -> consecutive tt -> one 8B store
                    us4 u;
#pragma unroll
                    for (int r = 0; r < 4; ++r) u[r] = f2bf(acc[i][j][r] + bv);
                    *(us4*)(Vt + (bh * 64 + d) * T_ + tt0) = u;
                } else {
                    unsigned short* dst = (which == 0) ? Qp : Kp;
#pragma unroll
                    for (int r = 0; r < 4; ++r)
                        dst[(bh * T_ + tt0 + r) * 64 + d] = f2bf(acc[i][j][r] + bv);
                }
            }
        }
    } else {
#pragma unroll
        for (int i = 0; i < MFR; ++i) {
#pragma unroll
            for (int j = 0; j < 4; ++j) {
                int col = n0 + wn * 64 + j * 16 + lrow;
                if (col >= N) continue;
                float bv = (bias && (SPLITK == 1 || chunk == 0)) ? bias[col] : 0.f;
#pragma unroll
                for (int r = 0; r < 4; ++r) {
                    int row = m0 + wm * (MT / WM) + i * 16 + r0 + r;
                    float v = acc[i][j][r] + bv;
                    if (GELU) {
                        float t = 0.7978845608028654f * (v + 0.044715f * v * v * v);
                        v = 0.5f * v * (1.f + tanhf(t));
                    }
                    if (RESID) v += resid[(size_t)row * N + col];
                    if (ATOMIC) {
                        atomicAdd(&((float*)Cout)[(size_t)row * N + col], v);
                    } else if (OUTBF) {
                        ((unsigned short*)Cout)[(size_t)row * N + col] = f2bf(v);
                    } else {
                        ((float*)Cout)[(size_t)row * N + col] = v;
                    }
                }
            }
        }
    }
    if (LOSSP) {
        // plain exp-sum per row over this panel (logits O(4); fp32-safe without max-shift)
#pragma unroll
        for (int i = 0; i < MFR; ++i) {
#pragma unroll
            for (int r = 0; r < 4; ++r) {
                float ss = 0.f;
#pragma unroll
                for (int j = 0; j < 4; ++j) {
                    int col = n0 + wn * 64 + j * 16 + lrow;
                    if (col < V_) ss += __expf(acc[i][j][r]);
                }
#pragma unroll
                for (int d2 = 1; d2 < 16; d2 <<= 1) ss += __shfl_xor(ss, d2, 64);
                if ((lane & 15) == 0) {
                    int rloc = wm * (MT / WM) + i * 16 + g * 4 + r;
                    Lsum[wn][rloc] = ss;
                }
            }
        }
        __syncthreads();
        if (tid < MT) {
            float ss = Lsum[0][tid];
#pragma unroll
            for (int ww = 1; ww < WN; ++ww) ss += Lsum[ww][tid];
            lpart[(size_t)(m0 + tid) * NPAN + npan] = ss;
        }
    }
}

// ---------------- MFMA flash attention: wave-owned q-tiles, 2-deep QK pipeline ----------
__global__ __launch_bounds__(256) void flash_attn_kernel(
    const unsigned short* __restrict__ Qp, const unsigned short* __restrict__ Kp,
    const unsigned short* __restrict__ Vt, unsigned short* __restrict__ y)
{
    int bid = blockIdx.x;
    int xcd = bid & 7;
    int s_ = bid >> 3;                 // 0..47
    int bh = xcd * 6 + (s_ % 6);       // 6 heads per XCD for KV L2 locality
    int qg = 7 - s_ / 6;               // heavy (large q) first
    int b = bh / H_, h = bh % H_;
    int tid = threadIdx.x;
    int w = tid >> 6;
    int lane = tid & 63;
    int c = lane & 15, g = lane >> 4;
    int q0 = (qg * 4 + w) * 16;        // this wave's q-tile

    const unsigned short* Qb = Qp + ((size_t)bh * T_ + q0) * 64;
    const unsigned short* Kb = Kp + (size_t)bh * T_ * 64;
    const unsigned short* Vb = Vt + (size_t)bh * 64 * T_;

    short8 qf0 = *(const short8*)(Qb + (size_t)c * 64 + g * 8);
    short8 qf1 = *(const short8*)(Qb + (size_t)c * 64 + 32 + g * 8);

    f32x4 o[4] = {};
    float mrow[4], lrow[4];
#pragma unroll
    for (int r = 0; r < 4; ++r) { mrow[r] = -1e30f; lrow[r] = 0.f; }

    __shared__ unsigned short P_lds[4][16 * 40];

    auto qk_tile = [&](int kv0, f32x4& t0, f32x4& t1) {
        t0 = (f32x4){0.f, 0.f, 0.f, 0.f};
        t1 = (f32x4){0.f, 0.f, 0.f, 0.f};
        const unsigned short* Kt0 = Kb + (size_t)(kv0 + c) * 64;
        short8 b0 = *(const short8*)(Kt0 + g * 8);
        short8 b1 = *(const short8*)(Kt0 + 32 + g * 8);
        const unsigned short* Kt1 = Kb + (size_t)(kv0 + 16 + c) * 64;
        short8 b2 = *(const short8*)(Kt1 + g * 8);
        short8 b3 = *(const short8*)(Kt1 + 32 + g * 8);
        __builtin_amdgcn_s_setprio(1);
        t0 = __builtin_amdgcn_mfma_f32_16x16x32_bf16(qf0, b0, t0, 0, 0, 0);
        t0 = __builtin_amdgcn_mfma_f32_16x16x32_bf16(qf1, b1, t0, 0, 0, 0);
        t1 = __builtin_amdgcn_mfma_f32_16x16x32_bf16(qf0, b2, t1, 0, 0, 0);
        t1 = __builtin_amdgcn_mfma_f32_16x16x32_bf16(qf1, b3, t1, 0, 0, 0);
        __builtin_amdgcn_s_setprio(0);
    };

    int ntiles = q0 / 32 + 1;
    f32x4 sN0, sN1;
    qk_tile(0, sN0, sN1);
    for (int t = 0; t < ntiles; ++t) {
        int kv0 = t * 32;
        f32x4 s0 = sN0, s1 = sN1;
        if (t + 1 < ntiles) qk_tile(kv0 + 32, sN0, sN1);   // overlap next QK with softmax below
        if (kv0 + 32 > q0) {
#pragma unroll
            for (int r = 0; r < 4; ++r) {
                int qq = q0 + g * 4 + r;
                float v0 = s0[r] * 0.125f;
                float v1 = s1[r] * 0.125f;
                s0[r] = (kv0 + c <= qq) ? v0 : -1e30f;
                s1[r] = (kv0 + 16 + c <= qq) ? v1 : -1e30f;
            }
        } else {
#pragma unroll
            for (int r = 0; r < 4; ++r) { s0[r] *= 0.125f; s1[r] *= 0.125f; }
        }
        float pmax[4];
#pragma unroll
        for (int r = 0; r < 4; ++r) pmax[r] = fmaxf(s0[r], s1[r]);
#pragma unroll
        for (int d2 = 1; d2 < 16; d2 <<= 1)
#pragma unroll
            for (int r = 0; r < 4; ++r) pmax[r] = fmaxf(pmax[r], __shfl_xor(pmax[r], d2, 64));
        float scl[4], psum[4];
#pragma unroll
        for (int r = 0; r < 4; ++r) {
            float mnew = fmaxf(mrow[r], pmax[r]);
            scl[r] = __expf(mrow[r] - mnew);
            mrow[r] = mnew;
            s0[r] = __expf(s0[r] - mnew);
            s1[r] = __expf(s1[r] - mnew);
            psum[r] = s0[r] + s1[r];
        }
#pragma unroll
        for (int d2 = 1; d2 < 16; d2 <<= 1)
#pragma unroll
            for (int r = 0; r < 4; ++r) psum[r] += __shfl_xor(psum[r], d2, 64);
#pragma unroll
        for (int r = 0; r < 4; ++r) lrow[r] = lrow[r] * scl[r] + psum[r];
#pragma unroll
        for (int j = 0; j < 4; ++j)
#pragma unroll
            for (int r = 0; r < 4; ++r) o[j][r] *= scl[r];
#pragma unroll
        for (int r = 0; r < 4; ++r) {
            P_lds[w][(g * 4 + r) * 40 + c] = f2bf(s0[r]);
            P_lds[w][(g * 4 + r) * 40 + 16 + c] = f2bf(s1[r]);
        }
        asm volatile("s_waitcnt lgkmcnt(0)" ::: "memory");
        __builtin_amdgcn_sched_barrier(0);
        short8 pf = *(const short8*)&P_lds[w][c * 40 + g * 8];
        asm volatile("s_waitcnt lgkmcnt(0)" ::: "memory");
        asm volatile("" ::: "memory");
        __builtin_amdgcn_s_setprio(1);
#pragma unroll
        for (int j = 0; j < 4; ++j) {
            short8 vf = *(const short8*)(Vb + (size_t)(j * 16 + c) * T_ + kv0 + g * 8);
            o[j] = __builtin_amdgcn_mfma_f32_16x16x32_bf16(pf, vf, o[j], 0, 0, 0);
        }
        __builtin_amdgcn_s_setprio(0);
    }
    unsigned short* yb = y + ((size_t)(b * T_ + q0)) * C_ + h * 64;
#pragma unroll
    for (int r = 0; r < 4; ++r) {
        float inv = 1.f / lrow[r];
#pragma unroll
        for (int j = 0; j < 4; ++j)
            yb[(size_t)(g * 4 + r) * C_ + j * 16 + c] = f2bf(o[j][r] * inv);
    }
}

// ---------------- loss: per-row nll (no atomics) + tiny final sum ----------------
__global__ __launch_bounds__(256) void loss_reduce_kernel(
    const float* __restrict__ lpart, const float* __restrict__ logits,
    const int* __restrict__ targets, float* __restrict__ rnll, int NPAN)
{
    int row = blockIdx.x;
    const float* pp = lpart + (size_t)row * NPAN;
    int tid = threadIdx.x;
    float s = 0.f;
    for (int j = tid; j < NPAN; j += 256) s += pp[j];
    for (int off = 32; off > 0; off >>= 1) s += __shfl_down(s, off, 64);
    __shared__ float rs[4];
    if ((tid & 63) == 0) rs[tid >> 6] = s;
    __syncthreads();
    if (tid == 0) {
        float S = rs[0] + rs[1] + rs[2] + rs[3];
        int t = targets[row];
        if (t != -100) {
            rnll[row] = -(logits[(size_t)row * V_ + t] - logf(S));
            rnll[M_ + row] = 1.f;
        } else {
            rnll[row] = 0.f;
            rnll[M_ + row] = 0.f;
        }
    }
}

__global__ __launch_bounds__(256) void finalize_loss(
    const float* __restrict__ rnll, float* __restrict__ out)
{
    int tid = threadIdx.x;
    float sn = 0.f, sc = 0.f;
    for (int j = tid; j < M_; j += 256) { sn += rnll[j]; sc += rnll[M_ + j]; }
    for (int off = 32; off > 0; off >>= 1) {
        sn += __shfl_down(sn, off, 64);
        sc += __shfl_down(sc, off, 64);
    }
    __shared__ float rn[4], rc[4];
    if ((tid & 63) == 0) { rn[tid >> 6] = sn; rc[tid >> 6] = sc; }
    __syncthreads();
    if (tid == 0) {
        float N = rn[0] + rn[1] + rn[2] + rn[3];
        float Cn = rc[0] + rc[1] + rc[2] + rc[3];
        out[0] = N / fmaxf(Cn, 1.f);
    }
}

extern "C" void kernel_launch(void* const* d_in, const int* in_sizes, int n_in,
                              void* d_out, int out_size, void* d_ws, size_t ws_size,
                              hipStream_t stream)
{
    const int*   idx     = (const int*)d_in[0];
    const int*   targets = (const int*)d_in[1];
    const float* wte     = (const float*)d_in[2];
    const float* wpe     = (const float*)d_in[3];
    const float* ln1_w   = (const float*)d_in[4];
    const float* ln1_b   = (const float*)d_in[5];
    const float* attn_w  = (const float*)d_in[6];
    const float* attn_b  = (const float*)d_in[7];
    const float* attnp_w = (const float*)d_in[8];
    const float* attnp_b = (const float*)d_in[9];
    const float* ln2_w   = (const float*)d_in[10];
    const float* ln2_b   = (const float*)d_in[11];
    const float* fc_w    = (const float*)d_in[12];
    const float* fc_b    = (const float*)d_in[13];
    const float* fcp_w   = (const float*)d_in[14];
    const float* fcp_b   = (const float*)d_in[15];
    const float* lnf_w   = (const float*)d_in[16];
    const float* lnf_b   = (const float*)d_in[17];
    const float* lm_w    = (const float*)d_in[18];

    float* logits = (float*)d_out;                    // [M_, V_]
    float* loss   = logits + (size_t)M_ * V_;         // 1 float

    // ---- workspace layout ----
    char* p = (char*)d_ws;
    __hip_bfloat16* aw_t = (__hip_bfloat16*)p; p += (size_t)L_ * 3 * C_ * C_ * 2;
    __hip_bfloat16* pw_t = (__hip_bfloat16*)p; p += (size_t)L_ * C_ * C_ * 2;
    __hip_bfloat16* fw_t = (__hip_bfloat16*)p; p += (size_t)L_ * FF_ * C_ * 2;
    __hip_bfloat16* qw_t = (__hip_bfloat16*)p; p += (size_t)L_ * C_ * FF_ * 2;
    __hip_bfloat16* lm_t = (__hip_bfloat16*)p; p += (size_t)VP2_ * C_ * 2;
    float*          x    = (float*)p;          p += (size_t)M_ * C_ * 4;
    __hip_bfloat16* h    = (__hip_bfloat16*)p; p += (size_t)M_ * C_ * 2;
    __hip_bfloat16* y    = (__hip_bfloat16*)p; p += (size_t)M_ * C_ * 2;
    __hip_bfloat16* ff   = (__hip_bfloat16*)p; p += (size_t)M_ * FF_ * 2;
    unsigned short* Qp   = (unsigned short*)p; p += (size_t)BH_ * T_ * 64 * 2;
    unsigned short* Kp   = (unsigned short*)p; p += (size_t)BH_ * T_ * 64 * 2;
    unsigned short* Vt   = (unsigned short*)p; p += (size_t)BH_ * 64 * T_ * 2;
    float*          lpart= (float*)p;          p += (size_t)M_ * NPAN_LM * 4;
    float*          rnll = (float*)p;          p += (size_t)2 * M_ * 4;

    // ---- fused weight convert+transpose (1 dispatch) ----
    transpose_all_kernel<<<30192, 256, 0, stream>>>(
        attn_w, aw_t, attnp_w, pw_t, fc_w, fw_t, fcp_w, qw_t, lm_w, lm_t);

    // ---- embedding (vectorized) ----
    {
        int total4 = M_ * C_ / 4;
        embed_kernel<<<(total4 + 255) / 256, 256, 0, stream>>>(idx, wte, wpe, x, total4);
    }

    for (int l = 0; l < L_; ++l) {
        const float* l1w = ln1_w + (size_t)l * C_;
        const float* l1b = ln1_b + (size_t)l * C_;
        const __hip_bfloat16* aw = aw_t + (size_t)l * 3 * C_ * C_;
        const float* ab  = attn_b + (size_t)l * 3 * C_;
        const __hip_bfloat16* pw = pw_t + (size_t)l * C_ * C_;
        const float* pb  = attnp_b + (size_t)l * C_;
        const float* l2w = ln2_w + (size_t)l * C_;
        const float* l2b = ln2_b + (size_t)l * C_;
        const __hip_bfloat16* fw = fw_t + (size_t)l * FF_ * C_;
        const float* fb  = fc_b + (size_t)l * FF_;
        const __hip_bfloat16* qw = qw_t + (size_t)l * C_ * FF_;
        const float* qb  = fcp_b + (size_t)l * C_;

        layernorm_kernel<<<M_ / 4, 256, 0, stream>>>(x, l1w, l1b, h);
        // qkv GEMM, MT=64, BUFS=2 (24.6KB LDS -> 6 blocks/CU; 576 blocks)
        mfma_gemm<64, 128, 2, 2, 2, 1, 0, 0, 0, 0, 1, 0><<<18 * 32, 256, 0, stream>>>(
            h, aw, ab, nullptr, nullptr, M_, 3 * C_, C_, 18, nullptr, 0, Qp, Kp, Vt);
        flash_attn_kernel<<<384, 256, 0, stream>>>(Qp, Kp, Vt, (unsigned short*)y);
        // proj: split-K=2, BUFS=2, atomic in-place residual accumulate into x (384 blocks)
        mfma_gemm<64, 128, 2, 2, 2, 2, 0, 0, 0, 0, 0, 1><<<6 * 32 * 2, 256, 0, stream>>>(
            y, pw, pb, nullptr, x, M_, C_, C_, 6, nullptr, 0, nullptr, nullptr, nullptr);
        layernorm_kernel<<<M_ / 4, 256, 0, stream>>>(x, l2w, l2b, h);
        // fc: MT=64, BUFS=2 (768 blocks, 6 blocks/CU)
        mfma_gemm<64, 128, 2, 2, 2, 1, 1, 1, 0, 0, 0, 0><<<24 * 32, 256, 0, stream>>>(
            h, fw, fb, nullptr, ff, M_, FF_, C_, 24, nullptr, 0, nullptr, nullptr, nullptr);
        // fc2: split-K=4, BUFS=2, atomic in-place residual accumulate into x (768 blocks)
        mfma_gemm<64, 128, 2, 2, 2, 4, 0, 0, 0, 0, 0, 1><<<6 * 32 * 4, 256, 0, stream>>>(
            ff, qw, qb, nullptr, x, M_, C_, FF_, 6, nullptr, 0, nullptr, nullptr, nullptr);
    }

    layernorm_kernel<<<M_ / 4, 256, 0, stream>>>(x, lnf_w, lnf_b, h);
    // lm-head: 128x256 tile, 8 waves, BUFS=2 (51.2KB LDS -> 3 blocks/CU), fused exp-sum
    mfma_gemm<128, 256, 2, 4, 2, 1, 0, 0, 0, 1, 0, 0><<<NPAN_LM * 16, 512, 0, stream>>>(
        h, lm_t, nullptr, nullptr, logits, M_, V_, C_, NPAN_LM, lpart, NPAN_LM,
        nullptr, nullptr, nullptr);

    loss_reduce_kernel<<<M_, 256, 0, stream>>>(lpart, logits, targets, rnll, NPAN_LM);
    finalize_loss<<<1, 256, 0, stream>>>(rnll, loss);
}

// Round 17
// 2081.384 us; speedup vs baseline: 1.0555x; 1.0555x over previous
//
#include <hip/hip_runtime.h>
#include <hip/hip_bf16.h>
#include <math.h>

#define L_ 12
#define C_ 768
#define H_ 12
#define FF_ 3072
#define V_ 50257
#define VP2_ 50432   // V padded to multiple of 256
#define T_ 512
#define B_ 4
#define D_ 64
#define M_ (B_*T_)   // 2048 rows
#define BH_ (B_*H_)  // 48
#define NPAN_LM 197  // VP2_/256

typedef __attribute__((ext_vector_type(8))) short short8;
typedef __attribute__((ext_vector_type(4))) float f32x4;
typedef __attribute__((ext_vector_type(8))) unsigned short us8;
typedef __attribute__((ext_vector_type(4))) unsigned short us4;

__device__ __forceinline__ float bf2f(unsigned short u) {
    return __uint_as_float(((unsigned)u) << 16);
}
__device__ __forceinline__ unsigned short f2bf(float f) {
    unsigned u = __float_as_uint(f);
    unsigned r = u + 0x7fff + ((u >> 16) & 1);   // RNE
    return (unsigned short)(r >> 16);
}

// ---------------- fused weight convert+transpose (all 5 weight groups, 1 dispatch) ---------
__device__ __forceinline__ void transpose_tile(
    const float* __restrict__ W, __hip_bfloat16* __restrict__ WT,
    int K, int N, int Npad, int bx, int by, int bz)
{
    __shared__ float tile[64][65];
    const float* Wl = W + (size_t)bz * K * N;
    __hip_bfloat16* WTl = WT + (size_t)bz * Npad * K;
    int k0 = by * 64, n0 = bx * 64;
    int tid = threadIdx.x;
    int tn = tid & 63, tk4 = tid >> 6;
#pragma unroll 4
    for (int i = 0; i < 16; ++i) {
        int k = tk4 * 16 + i;
        int n = n0 + tn;
        tile[k][tn] = (n < N) ? Wl[(size_t)(k0 + k) * N + n] : 0.f;
    }
    __syncthreads();
#pragma unroll
    for (int i = 0; i < 2; ++i) {
        int p = tid + i * 256;
        int n = p >> 3;
        int k8 = (p & 7) * 8;
        us8 v;
#pragma unroll
        for (int e = 0; e < 8; ++e) v[e] = f2bf(tile[k8 + e][n]);
        *(us8*)((unsigned short*)WTl + (size_t)(n0 + n) * K + k0 + k8) = v;
    }
}

__global__ __launch_bounds__(256) void transpose_all_kernel(
    const float* W0, __hip_bfloat16* T0,
    const float* W1, __hip_bfloat16* T1,
    const float* W2, __hip_bfloat16* T2,
    const float* W3, __hip_bfloat16* T3,
    const float* W4, __hip_bfloat16* T4)
{
    int bid = blockIdx.x;
    if (bid < 5184) {
        int bx = bid % 36, r = bid / 36;
        transpose_tile(W0, T0, C_, 3 * C_, 3 * C_, bx, r % 12, r / 12);
    } else if (bid < 6912) {
        int lb = bid - 5184;
        int bx = lb % 12, r = lb / 12;
        transpose_tile(W1, T1, C_, C_, C_, bx, r % 12, r / 12);
    } else if (bid < 13824) {
        int lb = bid - 6912;
        int bx = lb % 48, r = lb / 48;
        transpose_tile(W2, T2, C_, FF_, FF_, bx, r % 12, r / 12);
    } else if (bid < 20736) {
        int lb = bid - 13824;
        int bx = lb % 12, r = lb / 12;
        transpose_tile(W3, T3, FF_, C_, C_, bx, r % 48, r / 48);
    } else {
        int lb = bid - 20736;
        int bx = lb % 788, by = lb / 788;
        transpose_tile(W4, T4, C_, V_, VP2_, bx, by, 0);
    }
}

// ---------------- embedding (fp32 residual stream), vectorized f32x4 ----------------
__global__ __launch_bounds__(256) void embed_kernel(
    const int* __restrict__ idx, const float* __restrict__ wte,
    const float* __restrict__ wpe, float* __restrict__ x, int total4)
{
    int i = blockIdx.x * blockDim.x + threadIdx.x;
    if (i >= total4) return;
    const int CQ = C_ / 4;
    int c4 = (i % CQ) * 4;
    int row = i / CQ;
    int t = row % T_;
    f32x4 a = *(const f32x4*)(wte + (size_t)idx[row] * C_ + c4);
    f32x4 b = *(const f32x4*)(wpe + (size_t)t * C_ + c4);
    *(f32x4*)(x + (size_t)row * C_ + c4) = a + b;
}

// ---------------- layernorm: wave-per-row, zero barriers ----------------
__global__ __launch_bounds__(256) void layernorm_kernel(
    const float* __restrict__ x, const float* __restrict__ w, const float* __restrict__ b,
    __hip_bfloat16* __restrict__ out)
{
    int wv = threadIdx.x >> 6, lane = threadIdx.x & 63;
    int row = blockIdx.x * 4 + wv;
    const float* xr = x + (size_t)row * C_;
    f32x4 v[3];
    float s = 0.f;
#pragma unroll
    for (int j = 0; j < 3; ++j) {
        v[j] = *(const f32x4*)(xr + j * 256 + lane * 4);
        s += v[j][0] + v[j][1] + v[j][2] + v[j][3];
    }
#pragma unroll
    for (int off = 32; off; off >>= 1) s += __shfl_xor(s, off, 64);
    float mean = s * (1.f / (float)C_);
    float var = 0.f;
#pragma unroll
    for (int j = 0; j < 3; ++j)
#pragma unroll
        for (int e = 0; e < 4; ++e) { float d = v[j][e] - mean; var += d * d; }
#pragma unroll
    for (int off = 32; off; off >>= 1) var += __shfl_xor(var, off, 64);
    float rstd = rsqrtf(var * (1.f / (float)C_) + 1e-5f);
    unsigned short* o = (unsigned short*)out + (size_t)row * C_;
#pragma unroll
    for (int j = 0; j < 3; ++j) {
        int c0 = j * 256 + lane * 4;
        f32x4 wv4 = *(const f32x4*)(w + c0);
        f32x4 bv4 = *(const f32x4*)(b + c0);
        us4 u;
#pragma unroll
        for (int e = 0; e < 4; ++e)
            u[e] = f2bf((v[j][e] - mean) * rstd * wv4[e] + bv4[e]);
        *(us4*)(o + c0) = u;
    }
}

// ---------------- bf16 MFMA GEMM, pipelined + LDS-swizzled ----------------
// MT x NT tile, WM x WN waves, BK=32, BUFS-buffer LDS, depth-(BUFS-1) prefetch,
// tail-aware counted vmcnt, bijective XCD swizzle (m204). SPLITK chunks the K range;
// ATOMIC: fp32 atomic residual accumulate. REPACK (lm-head): reuse staging LDS to emit
// 256B-coalesced fp32 row stores + fused per-row exp-sum (fixes 64B-segment write pattern).
template<int MT, int NT, int WM, int WN, int BUFS, int SPLITK,
         int OUTBF, int GELU, int RESID, int LOSSP, int QKVPACK, int ATOMIC, int REPACK>
__global__ __launch_bounds__(64 * WM * WN) void mfma_gemm(
    const __hip_bfloat16* __restrict__ A,
    const __hip_bfloat16* __restrict__ Bt,
    const float* __restrict__ bias,
    const float* __restrict__ resid,
    void* __restrict__ Cout,
    int M, int N, int K, int NB,
    float* __restrict__ lpart, int NPAN,
    unsigned short* __restrict__ Qp, unsigned short* __restrict__ Kp,
    unsigned short* __restrict__ Vt)
{
    constexpr int NTHREADS = 64 * WM * WN;
    constexpr int MPAN = M_ / MT;
    constexpr int MFR = MT / (16 * WM);      // per-wave m-fragments
    constexpr int AL = (MT * 4) / NTHREADS;
    constexpr int BL = (NT * 4) / NTHREADS;
    constexpr int LOADS = AL + BL;
    constexpr int SMEM_STAGE = BUFS * (MT + NT) * 32 * 2;           // bytes
    constexpr int SMEM_LS = (LOSSP && !REPACK) ? WN * MT * 4 : 4;
    constexpr int SMEM_RPK = REPACK ? 64 * 264 * 4 : 0;
    constexpr int SMEM_TOT = (SMEM_STAGE + SMEM_LS) > SMEM_RPK ? (SMEM_STAGE + SMEM_LS) : SMEM_RPK;

    int nwg = NB * MPAN * SPLITK;
    int orig = blockIdx.x;
    int xcd = orig & 7;
    int q = nwg >> 3, rr_ = nwg & 7;
    int wgid = (xcd < rr_ ? xcd * (q + 1) : rr_ * (q + 1) + (xcd - rr_) * q) + (orig >> 3);
    int chunk = wgid / (NB * MPAN);
    int rem = wgid % (NB * MPAN);
    int npan = rem / MPAN, mpan = rem % MPAN;
    int m0 = mpan * MT, n0 = npan * NT;
    int KC = K / SPLITK;
    int kbase = chunk * KC;

    __shared__ char smem[SMEM_TOT];
    __hip_bfloat16* AsB = (__hip_bfloat16*)smem;                        // [BUFS][MT*32]
    __hip_bfloat16* BsB = (__hip_bfloat16*)(smem + BUFS * MT * 32 * 2); // [BUFS][NT*32]
    float* Lsum = (float*)(smem + SMEM_STAGE);                          // [WN][MT]
    float* tileF = (float*)smem;                                        // [64][264]
    int tid = threadIdx.x;
    int lane = tid & 63, w = tid >> 6;
    int wn = w % WN, wm = w / WN;
    int lrow = lane & 15, g = lane >> 4;
    f32x4 acc[MFR][4] = {};

    const __hip_bfloat16* Ab = A + (size_t)m0 * K + kbase;
    const __hip_bfloat16* Bb = Bt + (size_t)n0 * K + kbase;

    auto stage = [&](int buf, int k0) {
#pragma unroll
        for (int i = 0; i < AL; ++i) {
            int c = tid + i * NTHREADS;
            int row = c >> 2, s = c & 3;
            int l = (s - (row >> 1)) & 3;            // inverse-swizzled source slot
            __builtin_amdgcn_global_load_lds(
                (const __attribute__((address_space(1))) void*)(Ab + (size_t)row * K + k0 + l * 8),
                (__attribute__((address_space(3))) void*)(&AsB[buf * MT * 32 + c * 8]), 16, 0, 0);
        }
#pragma unroll
        for (int i = 0; i < BL; ++i) {
            int c = tid + i * NTHREADS;
            int row = c >> 2, s = c & 3;
            int l = (s - (row >> 1)) & 3;
            __builtin_amdgcn_global_load_lds(
                (const __attribute__((address_space(1))) void*)(Bb + (size_t)row * K + k0 + l * 8),
                (__attribute__((address_space(3))) void*)(&BsB[buf * NT * 32 + c * 8]), 16, 0, 0);
        }
    };
    auto do_tile = [&](int buf) {
        short8 a[MFR], b[4];
#pragma unroll
        for (int i = 0; i < MFR; ++i) {
            int row = wm * (MT / WM) + i * 16 + lrow;
            int s = (g + (row >> 1)) & 3;            // swizzled read slot
            a[i] = *(const short8*)&AsB[buf * MT * 32 + row * 32 + s * 8];
        }
#pragma unroll
        for (int j = 0; j < 4; ++j) {
            int row = wn * 64 + j * 16 + lrow;
            int s = (g + (row >> 1)) & 3;
            b[j] = *(const short8*)&BsB[buf * NT * 32 + row * 32 + s * 8];
        }
        asm volatile("s_waitcnt lgkmcnt(0)" ::: "memory");
        __builtin_amdgcn_sched_barrier(0);
        __builtin_amdgcn_s_setprio(1);
#pragma unroll
        for (int i = 0; i < MFR; ++i)
#pragma unroll
            for (int j = 0; j < 4; ++j)
                acc[i][j] = __builtin_amdgcn_mfma_f32_16x16x32_bf16(a[i], b[j], acc[i][j], 0, 0, 0);
        __builtin_amdgcn_s_setprio(0);
    };

    int nk = KC >> 5;
#pragma unroll
    for (int i = 0; i < BUFS - 1; ++i) stage(i, i << 5);
    for (int t = 0; t < nk; ++t) {
        int ahead = nk - 1 - t;
        if (ahead > BUFS - 2) ahead = BUFS - 2;
        if (ahead == 1) {
            if constexpr (LOADS == 3) asm volatile("s_waitcnt vmcnt(3)" ::: "memory");
            else                      asm volatile("s_waitcnt vmcnt(4)" ::: "memory");
        } else if (ahead >= 2) {
            if constexpr (LOADS == 3) asm volatile("s_waitcnt vmcnt(6)" ::: "memory");
            else                      asm volatile("s_waitcnt vmcnt(8)" ::: "memory");
        } else {
            asm volatile("s_waitcnt vmcnt(0)" ::: "memory");
        }
        __builtin_amdgcn_s_barrier();
        if (t + BUFS - 1 < nk) stage((t + BUFS - 1) % BUFS, (t + BUFS - 1) << 5);
        do_tile(t % BUFS);
    }

    int r0 = g * 4;
    if constexpr (REPACK) {
        // lm-head path: fp32 out, no bias/gelu/resid; coalesced 256B row stores via LDS.
        float* logitsF = (float*)Cout;
        __syncthreads();
#pragma unroll
        for (int half = 0; half < 2; ++half) {
            if (wm == half) {
#pragma unroll
                for (int i = 0; i < MFR; ++i)
#pragma unroll
                    for (int j = 0; j < 4; ++j)
#pragma unroll
                        for (int r = 0; r < 4; ++r)
                            tileF[(i * 16 + r0 + r) * 264 + wn * 64 + j * 16 + lrow] = acc[i][j][r];
            }
            __syncthreads();
#pragma unroll
            for (int it = 0; it < 64 / (NTHREADS / 64); ++it) {
                int rw = it * (NTHREADS / 64) + (tid >> 6);
                int grow = m0 + half * 64 + rw;
                float ss = 0.f;
#pragma unroll
                for (int e = 0; e < 4; ++e) {
                    int cl = (tid & 63) + e * 64;        // 0..255, lane-contiguous
                    float v = tileF[rw * 264 + cl];
                    int gcol = n0 + cl;
                    if (gcol < V_) {
                        logitsF[(size_t)grow * V_ + gcol] = v;
                        ss += __expf(v);
                    }
                }
#pragma unroll
                for (int d2 = 1; d2 < 64; d2 <<= 1) ss += __shfl_xor(ss, d2, 64);
                if ((tid & 63) == 0) lpart[(size_t)grow * NPAN + npan] = ss;
            }
            __syncthreads();
        }
        return;
    }
    if (QKVPACK) {
        // which (q/k/v section) is block-uniform: n0 is 128-aligned, sections 768-aligned
        int which = n0 / 768;
#pragma unroll
        for (int i = 0; i < MFR; ++i) {
#pragma unroll
            for (int j = 0; j < 4; ++j) {
                int col = n0 + wn * 64 + j * 16 + lrow;
                float bv = bias ? bias[col] : 0.f;
                int cc = col - which * 768;
                int hh = cc >> 6, d = cc & 63;
                int row0 = m0 + wm * (MT / WM) + i * 16 + r0;
                int bb = row0 >> 9, tt0 = row0 & (T_ - 1);
                size_t bh = (size_t)bb * H_ + hh;
                if (which == 2) {
                    // V transposed: r=0..3 -> consecutive tt -> one 8B store
                    us4 u;
#pragma unroll
                    for (int r = 0; r < 4; ++r) u[r] = f2bf(acc[i][j][r] + bv);
                    *(us4*)(Vt + (bh * 64 + d) * T_ + tt0) = u;
                } else {
                    unsigned short* dst = (which == 0) ? Qp : Kp;
#pragma unroll
                    for (int r = 0; r < 4; ++r)
                        dst[(bh * T_ + tt0 + r) * 64 + d] = f2bf(acc[i][j][r] + bv);
                }
            }
        }
    } else {
#pragma unroll
        for (int i = 0; i < MFR; ++i) {
#pragma unroll
            for (int j = 0; j < 4; ++j) {
                int col = n0 + wn * 64 + j * 16 + lrow;
                if (col >= N) continue;
                float bv = (bias && (SPLITK == 1 || chunk == 0)) ? bias[col] : 0.f;
#pragma unroll
                for (int r = 0; r < 4; ++r) {
                    int row = m0 + wm * (MT / WM) + i * 16 + r0 + r;
                    float v = acc[i][j][r] + bv;
                    if (GELU) {
                        float t = 0.7978845608028654f * (v + 0.044715f * v * v * v);
                        v = 0.5f * v * (1.f + tanhf(t));
                    }
                    if (RESID) v += resid[(size_t)row * N + col];
                    if (ATOMIC) {
                        atomicAdd(&((float*)Cout)[(size_t)row * N + col], v);
                    } else if (OUTBF) {
                        ((unsigned short*)Cout)[(size_t)row * N + col] = f2bf(v);
                    } else {
                        ((float*)Cout)[(size_t)row * N + col] = v;
                    }
                }
            }
        }
    }
    if constexpr (LOSSP && !REPACK) {
#pragma unroll
        for (int i = 0; i < MFR; ++i) {
#pragma unroll
            for (int r = 0; r < 4; ++r) {
                float ss = 0.f;
#pragma unroll
                for (int j = 0; j < 4; ++j) {
                    int col = n0 + wn * 64 + j * 16 + lrow;
                    if (col < V_) ss += __expf(acc[i][j][r]);
                }
#pragma unroll
                for (int d2 = 1; d2 < 16; d2 <<= 1) ss += __shfl_xor(ss, d2, 64);
                if ((lane & 15) == 0) {
                    int rloc = wm * (MT / WM) + i * 16 + g * 4 + r;
                    Lsum[wn * MT + rloc] = ss;
                }
            }
        }
        __syncthreads();
        if (tid < MT) {
            float ss = Lsum[tid];
#pragma unroll
            for (int ww = 1; ww < WN; ++ww) ss += Lsum[ww * MT + tid];
            lpart[(size_t)(m0 + tid) * NPAN + npan] = ss;
        }
    }
}

// ---------------- MFMA flash attention: wave-owned q-tiles, 2-deep QK pipeline ----------
__global__ __launch_bounds__(256) void flash_attn_kernel(
    const unsigned short* __restrict__ Qp, const unsigned short* __restrict__ Kp,
    const unsigned short* __restrict__ Vt, unsigned short* __restrict__ y)
{
    int bid = blockIdx.x;
    int xcd = bid & 7;
    int s_ = bid >> 3;                 // 0..47
    int bh = xcd * 6 + (s_ % 6);       // 6 heads per XCD for KV L2 locality
    int qg = 7 - s_ / 6;               // heavy (large q) first
    int b = bh / H_, h = bh % H_;
    int tid = threadIdx.x;
    int w = tid >> 6;
    int lane = tid & 63;
    int c = lane & 15, g = lane >> 4;
    int q0 = (qg * 4 + w) * 16;        // this wave's q-tile

    const unsigned short* Qb = Qp + ((size_t)bh * T_ + q0) * 64;
    const unsigned short* Kb = Kp + (size_t)bh * T_ * 64;
    const unsigned short* Vb = Vt + (size_t)bh * 64 * T_;

    short8 qf0 = *(const short8*)(Qb + (size_t)c * 64 + g * 8);
    short8 qf1 = *(const short8*)(Qb + (size_t)c * 64 + 32 + g * 8);

    f32x4 o[4] = {};
    float mrow[4], lrow[4];
#pragma unroll
    for (int r = 0; r < 4; ++r) { mrow[r] = -1e30f; lrow[r] = 0.f; }

    __shared__ unsigned short P_lds[4][16 * 40];

    auto qk_tile = [&](int kv0, f32x4& t0, f32x4& t1) {
        t0 = (f32x4){0.f, 0.f, 0.f, 0.f};
        t1 = (f32x4){0.f, 0.f, 0.f, 0.f};
        const unsigned short* Kt0 = Kb + (size_t)(kv0 + c) * 64;
        short8 b0 = *(const short8*)(Kt0 + g * 8);
        short8 b1 = *(const short8*)(Kt0 + 32 + g * 8);
        const unsigned short* Kt1 = Kb + (size_t)(kv0 + 16 + c) * 64;
        short8 b2 = *(const short8*)(Kt1 + g * 8);
        short8 b3 = *(const short8*)(Kt1 + 32 + g * 8);
        __builtin_amdgcn_s_setprio(1);
        t0 = __builtin_amdgcn_mfma_f32_16x16x32_bf16(qf0, b0, t0, 0, 0, 0);
        t0 = __builtin_amdgcn_mfma_f32_16x16x32_bf16(qf1, b1, t0, 0, 0, 0);
        t1 = __builtin_amdgcn_mfma_f32_16x16x32_bf16(qf0, b2, t1, 0, 0, 0);
        t1 = __builtin_amdgcn_mfma_f32_16x16x32_bf16(qf1, b3, t1, 0, 0, 0);
        __builtin_amdgcn_s_setprio(0);
    };

    int ntiles = q0 / 32 + 1;
    f32x4 sN0, sN1;
    qk_tile(0, sN0, sN1);
    for (int t = 0; t < ntiles; ++t) {
        int kv0 = t * 32;
        f32x4 s0 = sN0, s1 = sN1;
        if (t + 1 < ntiles) qk_tile(kv0 + 32, sN0, sN1);   // overlap next QK with softmax below
        if (kv0 + 32 > q0) {
#pragma unroll
            for (int r = 0; r < 4; ++r) {
                int qq = q0 + g * 4 + r;
                float v0 = s0[r] * 0.125f;
                float v1 = s1[r] * 0.125f;
                s0[r] = (kv0 + c <= qq) ? v0 : -1e30f;
                s1[r] = (kv0 + 16 + c <= qq) ? v1 : -1e30f;
            }
        } else {
#pragma unroll
            for (int r = 0; r < 4; ++r) { s0[r] *= 0.125f; s1[r] *= 0.125f; }
        }
        float pmax[4];
#pragma unroll
        for (int r = 0; r < 4; ++r) pmax[r] = fmaxf(s0[r], s1[r]);
#pragma unroll
        for (int d2 = 1; d2 < 16; d2 <<= 1)
#pragma unroll
            for (int r = 0; r < 4; ++r) pmax[r] = fmaxf(pmax[r], __shfl_xor(pmax[r], d2, 64));
        float scl[4], psum[4];
#pragma unroll
        for (int r = 0; r < 4; ++r) {
            float mnew = fmaxf(mrow[r], pmax[r]);
            scl[r] = __expf(mrow[r] - mnew);
            mrow[r] = mnew;
            s0[r] = __expf(s0[r] - mnew);
            s1[r] = __expf(s1[r] - mnew);
            psum[r] = s0[r] + s1[r];
        }
#pragma unroll
        for (int d2 = 1; d2 < 16; d2 <<= 1)
#pragma unroll
            for (int r = 0; r < 4; ++r) psum[r] += __shfl_xor(psum[r], d2, 64);
#pragma unroll
        for (int r = 0; r < 4; ++r) lrow[r] = lrow[r] * scl[r] + psum[r];
#pragma unroll
        for (int j = 0; j < 4; ++j)
#pragma unroll
            for (int r = 0; r < 4; ++r) o[j][r] *= scl[r];
#pragma unroll
        for (int r = 0; r < 4; ++r) {
            P_lds[w][(g * 4 + r) * 40 + c] = f2bf(s0[r]);
            P_lds[w][(g * 4 + r) * 40 + 16 + c] = f2bf(s1[r]);
        }
        asm volatile("s_waitcnt lgkmcnt(0)" ::: "memory");
        __builtin_amdgcn_sched_barrier(0);
        short8 pf = *(const short8*)&P_lds[w][c * 40 + g * 8];
        asm volatile("s_waitcnt lgkmcnt(0)" ::: "memory");
        asm volatile("" ::: "memory");
        __builtin_amdgcn_s_setprio(1);
#pragma unroll
        for (int j = 0; j < 4; ++j) {
            short8 vf = *(const short8*)(Vb + (size_t)(j * 16 + c) * T_ + kv0 + g * 8);
            o[j] = __builtin_amdgcn_mfma_f32_16x16x32_bf16(pf, vf, o[j], 0, 0, 0);
        }
        __builtin_amdgcn_s_setprio(0);
    }
    unsigned short* yb = y + ((size_t)(b * T_ + q0)) * C_ + h * 64;
#pragma unroll
    for (int r = 0; r < 4; ++r) {
        float inv = 1.f / lrow[r];
#pragma unroll
        for (int j = 0; j < 4; ++j)
            yb[(size_t)(g * 4 + r) * C_ + j * 16 + c] = f2bf(o[j][r] * inv);
    }
}

// ---------------- loss: per-row nll (no atomics) + tiny final sum ----------------
__global__ __launch_bounds__(256) void loss_reduce_kernel(
    const float* __restrict__ lpart, const float* __restrict__ logits,
    const int* __restrict__ targets, float* __restrict__ rnll, int NPAN)
{
    int row = blockIdx.x;
    const float* pp = lpart + (size_t)row * NPAN;
    int tid = threadIdx.x;
    float s = 0.f;
    for (int j = tid; j < NPAN; j += 256) s += pp[j];
    for (int off = 32; off > 0; off >>= 1) s += __shfl_down(s, off, 64);
    __shared__ float rs[4];
    if ((tid & 63) == 0) rs[tid >> 6] = s;
    __syncthreads();
    if (tid == 0) {
        float S = rs[0] + rs[1] + rs[2] + rs[3];
        int t = targets[row];
        if (t != -100) {
            rnll[row] = -(logits[(size_t)row * V_ + t] - logf(S));
            rnll[M_ + row] = 1.f;
        } else {
            rnll[row] = 0.f;
            rnll[M_ + row] = 0.f;
        }
    }
}

__global__ __launch_bounds__(256) void finalize_loss(
    const float* __restrict__ rnll, float* __restrict__ out)
{
    int tid = threadIdx.x;
    float sn = 0.f, sc = 0.f;
    for (int j = tid; j < M_; j += 256) { sn += rnll[j]; sc += rnll[M_ + j]; }
    for (int off = 32; off > 0; off >>= 1) {
        sn += __shfl_down(sn, off, 64);
        sc += __shfl_down(sc, off, 64);
    }
    __shared__ float rn[4], rc[4];
    if ((tid & 63) == 0) { rn[tid >> 6] = sn; rc[tid >> 6] = sc; }
    __syncthreads();
    if (tid == 0) {
        float N = rn[0] + rn[1] + rn[2] + rn[3];
        float Cn = rc[0] + rc[1] + rc[2] + rc[3];
        out[0] = N / fmaxf(Cn, 1.f);
    }
}

extern "C" void kernel_launch(void* const* d_in, const int* in_sizes, int n_in,
                              void* d_out, int out_size, void* d_ws, size_t ws_size,
                              hipStream_t stream)
{
    const int*   idx     = (const int*)d_in[0];
    const int*   targets = (const int*)d_in[1];
    const float* wte     = (const float*)d_in[2];
    const float* wpe     = (const float*)d_in[3];
    const float* ln1_w   = (const float*)d_in[4];
    const float* ln1_b   = (const float*)d_in[5];
    const float* attn_w  = (const float*)d_in[6];
    const float* attn_b  = (const float*)d_in[7];
    const float* attnp_w = (const float*)d_in[8];
    const float* attnp_b = (const float*)d_in[9];
    const float* ln2_w   = (const float*)d_in[10];
    const float* ln2_b   = (const float*)d_in[11];
    const float* fc_w    = (const float*)d_in[12];
    const float* fc_b    = (const float*)d_in[13];
    const float* fcp_w   = (const float*)d_in[14];
    const float* fcp_b   = (const float*)d_in[15];
    const float* lnf_w   = (const float*)d_in[16];
    const float* lnf_b   = (const float*)d_in[17];
    const float* lm_w    = (const float*)d_in[18];

    float* logits = (float*)d_out;                    // [M_, V_]
    float* loss   = logits + (size_t)M_ * V_;         // 1 float

    // ---- workspace layout ----
    char* p = (char*)d_ws;
    __hip_bfloat16* aw_t = (__hip_bfloat16*)p; p += (size_t)L_ * 3 * C_ * C_ * 2;
    __hip_bfloat16* pw_t = (__hip_bfloat16*)p; p += (size_t)L_ * C_ * C_ * 2;
    __hip_bfloat16* fw_t = (__hip_bfloat16*)p; p += (size_t)L_ * FF_ * C_ * 2;
    __hip_bfloat16* qw_t = (__hip_bfloat16*)p; p += (size_t)L_ * C_ * FF_ * 2;
    __hip_bfloat16* lm_t = (__hip_bfloat16*)p; p += (size_t)VP2_ * C_ * 2;
    float*          x    = (float*)p;          p += (size_t)M_ * C_ * 4;
    __hip_bfloat16* h    = (__hip_bfloat16*)p; p += (size_t)M_ * C_ * 2;
    __hip_bfloat16* y    = (__hip_bfloat16*)p; p += (size_t)M_ * C_ * 2;
    __hip_bfloat16* ff   = (__hip_bfloat16*)p; p += (size_t)M_ * FF_ * 2;
    unsigned short* Qp   = (unsigned short*)p; p += (size_t)BH_ * T_ * 64 * 2;
    unsigned short* Kp   = (unsigned short*)p; p += (size_t)BH_ * T_ * 64 * 2;
    unsigned short* Vt   = (unsigned short*)p; p += (size_t)BH_ * 64 * T_ * 2;
    float*          lpart= (float*)p;          p += (size_t)M_ * NPAN_LM * 4;
    float*          rnll = (float*)p;          p += (size_t)2 * M_ * 4;

    // ---- fused weight convert+transpose (1 dispatch) ----
    transpose_all_kernel<<<30192, 256, 0, stream>>>(
        attn_w, aw_t, attnp_w, pw_t, fc_w, fw_t, fcp_w, qw_t, lm_w, lm_t);

    // ---- embedding (vectorized) ----
    {
        int total4 = M_ * C_ / 4;
        embed_kernel<<<(total4 + 255) / 256, 256, 0, stream>>>(idx, wte, wpe, x, total4);
    }

    for (int l = 0; l < L_; ++l) {
        const float* l1w = ln1_w + (size_t)l * C_;
        const float* l1b = ln1_b + (size_t)l * C_;
        const __hip_bfloat16* aw = aw_t + (size_t)l * 3 * C_ * C_;
        const float* ab  = attn_b + (size_t)l * 3 * C_;
        const __hip_bfloat16* pw = pw_t + (size_t)l * C_ * C_;
        const float* pb  = attnp_b + (size_t)l * C_;
        const float* l2w = ln2_w + (size_t)l * C_;
        const float* l2b = ln2_b + (size_t)l * C_;
        const __hip_bfloat16* fw = fw_t + (size_t)l * FF_ * C_;
        const float* fb  = fc_b + (size_t)l * FF_;
        const __hip_bfloat16* qw = qw_t + (size_t)l * C_ * FF_;
        const float* qb  = fcp_b + (size_t)l * C_;

        layernorm_kernel<<<M_ / 4, 256, 0, stream>>>(x, l1w, l1b, h);
        // qkv GEMM, MT=64 (576 blocks)
        mfma_gemm<64, 128, 2, 2, 3, 1, 0, 0, 0, 0, 1, 0, 0><<<18 * 32, 256, 0, stream>>>(
            h, aw, ab, nullptr, nullptr, M_, 3 * C_, C_, 18, nullptr, 0, Qp, Kp, Vt);
        flash_attn_kernel<<<384, 256, 0, stream>>>(Qp, Kp, Vt, (unsigned short*)y);
        // proj: split-K=2, atomic in-place residual accumulate into x (384 blocks)
        mfma_gemm<64, 128, 2, 2, 3, 2, 0, 0, 0, 0, 0, 1, 0><<<6 * 32 * 2, 256, 0, stream>>>(
            y, pw, pb, nullptr, x, M_, C_, C_, 6, nullptr, 0, nullptr, nullptr, nullptr);
        layernorm_kernel<<<M_ / 4, 256, 0, stream>>>(x, l2w, l2b, h);
        // fc: MT=64 (768 blocks)
        mfma_gemm<64, 128, 2, 2, 3, 1, 1, 1, 0, 0, 0, 0, 0><<<24 * 32, 256, 0, stream>>>(
            h, fw, fb, nullptr, ff, M_, FF_, C_, 24, nullptr, 0, nullptr, nullptr, nullptr);
        // fc2: split-K=4, atomic in-place residual accumulate into x (768 blocks)
        mfma_gemm<64, 128, 2, 2, 3, 4, 0, 0, 0, 0, 0, 1, 0><<<6 * 32 * 4, 256, 0, stream>>>(
            ff, qw, qb, nullptr, x, M_, C_, FF_, 6, nullptr, 0, nullptr, nullptr, nullptr);
    }

    layernorm_kernel<<<M_ / 4, 256, 0, stream>>>(x, lnf_w, lnf_b, h);
    // lm-head: 128x256 tile, 8 waves, REPACK epilogue (coalesced fp32 stores + fused exp-sum)
    mfma_gemm<128, 256, 2, 4, 3, 1, 0, 0, 0, 1, 0, 0, 1><<<NPAN_LM * 16, 512, 0, stream>>>(
        h, lm_t, nullptr, nullptr, logits, M_, V_, C_, NPAN_LM, lpart, NPAN_LM,
        nullptr, nullptr, nullptr);

    loss_reduce_kernel<<<M_, 256, 0, stream>>>(lpart, logits, targets, rnll, NPAN_LM);
    finalize_loss<<<1, 256, 0, stream>>>(rnll, loss);
}